// Round 12
// baseline (139.702 us; speedup 1.0000x reference)
//
#include <hip/hip_runtime.h>
#include <hip/hip_bf16.h>
#include <stdint.h>

typedef unsigned short u16;
typedef unsigned int   u32;
typedef short s16x8 __attribute__((ext_vector_type(8)));
typedef float f32x4 __attribute__((ext_vector_type(4)));

#define LDP 33409

__device__ __forceinline__ u16 f2bf(float f) {
    union { float f; u32 u; } v; v.f = f;
    u32 r = v.u + 0x7fffu + ((v.u >> 16) & 1u);
    return (u16)(r >> 16);
}
__device__ __forceinline__ float bf2f(u16 h) {
    union { u32 u; float f; } v; v.u = ((u32)h) << 16;
    return v.f;
}
__device__ __forceinline__ float fast_tanh(float x) {
    float e = __expf(2.0f * x);
    return 1.0f - 2.0f / (e + 1.0f);
}
__device__ __forceinline__ f32x4 MFMA(s16x8 a, s16x8 b, f32x4 c) {
    return __builtin_amdgcn_mfma_f32_16x16x32_bf16(a, b, c, 0, 0, 0);
}
__device__ __forceinline__ void gload_lds16(const void* g, void* l) {
    __builtin_amdgcn_global_load_lds(
        (const __attribute__((address_space(1))) u32*)(uintptr_t)g,
        (__attribute__((address_space(3))) u32*)(uintptr_t)l, 16, 0, 0);
}

// ---------------------------------------------------------------------------
// prep0: [0,128) cvt u -> ubf ; [128,160) transpose bw0 -> bw0t[1024][128]
// ---------------------------------------------------------------------------
__global__ __launch_bounds__(256)
void prep0(const float* __restrict__ u, const float* __restrict__ bw0,
           u16* __restrict__ ubf, u16* __restrict__ bw0t)
{
    __shared__ float tile[64][65];
    const int bid = blockIdx.x, tid = threadIdx.x;
    if (bid < 128) {
        int i = (bid * 256 + tid) * 8;
        float4 a = *(const float4*)&u[i];
        float4 b = *(const float4*)&u[i + 4];
        uint4 o;
        o.x = (u32)f2bf(a.x) | ((u32)f2bf(a.y) << 16);
        o.y = (u32)f2bf(a.z) | ((u32)f2bf(a.w) << 16);
        o.z = (u32)f2bf(b.x) | ((u32)f2bf(b.y) << 16);
        o.w = (u32)f2bf(b.z) | ((u32)f2bf(b.w) << 16);
        *(uint4*)&ubf[i] = o;
        return;
    }
    const int idx = bid - 128;
    const int rb = (idx >> 4) * 64, cb = (idx & 15) * 64;
    for (int i = tid; i < 64 * 64; i += 256) {
        int r = i >> 6, c = i & 63;
        tile[r][c] = bw0[(size_t)(rb + r) * 1024 + cb + c];
    }
    __syncthreads();
    for (int i = tid; i < 64 * 64; i += 256) {
        int c = i >> 6, r = i & 63;
        bw0t[(size_t)(cb + c) * 128 + rb + r] = f2bf(tile[r][c]);
    }
}

// ---------------------------------------------------------------------------
// Fused branch GEMM + horizontal prep.
// blocks [0,256): 128(M)x64(N) GEMM, BK=64  C = tanh(A @ Bt^T + bias)
//                 bn=(b&15)*64, bm=(b>>4)*128; 4 waves (2Mx2N).
// mode 0/1/2, blocks [256,512): transpose xsrc(1024^2) -> xdst[n][k]
// mode 2, blocks [512,1025):    BWt[n][k]=(bw4@W1)[k][n]; block 1024: bz
// mode 3, blocks [256,772):     gather trunk Bt[layer][n][p] (32-row tiles)
// ---------------------------------------------------------------------------
__global__ __launch_bounds__(256, 2)
void gemm_fused(const u16* __restrict__ A, int lda,
                const u16* __restrict__ Bt, int ldb,
                const float* __restrict__ bias,
                u16* __restrict__ Cout, int ldc, int K, int mode,
                const float* __restrict__ xsrc, u16* __restrict__ xdst,
                const float* __restrict__ bw4, const float* __restrict__ bb4,
                const float* __restrict__ W1, u16* __restrict__ BWt,
                float* __restrict__ bz,
                const float* __restrict__ W2, u16* __restrict__ Btb)
{
    __shared__ __align__(16) char lds[49152];
    const int bid = blockIdx.x, tid = threadIdx.x;

    if (bid < 256) {                           // ========== GEMM 128x64, BK=64
        u16 (*As)[128 * 64] = (u16(*)[128 * 64])lds;          // 2 x 16 KB
        u16 (*Bs)[64 * 64]  = (u16(*)[64 * 64])(lds + 32768); // 2 x 8 KB
        const int lane = tid & 63, wid = tid >> 6;
        const int wr = wid >> 1, wc = wid & 1;
        const int bn = (bid & 15) * 64, bm = (bid >> 4) * 128;
        const int NT = K >> 6;
        const int ch = tid & 7;                // k-chunk (8 x 16B per row)
        f32x4 acc[4][2] = {};

        auto STAGE = [&](int buf, int t) {
            const int k0 = t << 6;
            #pragma unroll
            for (int r = 0; r < 4; ++r) {       // A: 128 rows x 8 chunks
                const int row = (r * 256 + tid) >> 3;
                gload_lds16(A + (size_t)(bm + row) * lda + k0 + ((ch ^ (row & 7)) << 3),
                            (char*)As[buf] + r * 4096 + wid * 1024);
            }
            #pragma unroll
            for (int r = 0; r < 2; ++r) {       // B: 64 rows x 8 chunks
                const int row = (r * 256 + tid) >> 3;
                gload_lds16(Bt + (size_t)(bn + row) * ldb + k0 + ((ch ^ (row & 7)) << 3),
                            (char*)Bs[buf] + r * 4096 + wid * 1024);
            }
        };
        auto COMPUTE = [&](int buf) {
            #pragma unroll
            for (int ks = 0; ks < 2; ++ks) {
                s16x8 av[4], bv[2];
                #pragma unroll
                for (int mi = 0; mi < 4; ++mi) {
                    int row = wr * 64 + mi * 16 + (lane & 15);
                    int c = ks * 4 + (lane >> 4);
                    av[mi] = *(const s16x8*)&As[buf][row * 64 + ((c ^ (row & 7)) << 3)];
                }
                #pragma unroll
                for (int ni = 0; ni < 2; ++ni) {
                    int col = wc * 32 + ni * 16 + (lane & 15);
                    int c = ks * 4 + (lane >> 4);
                    bv[ni] = *(const s16x8*)&Bs[buf][col * 64 + ((c ^ (col & 7)) << 3)];
                }
                #pragma unroll
                for (int mi = 0; mi < 4; ++mi)
                #pragma unroll
                for (int ni = 0; ni < 2; ++ni)
                    acc[mi][ni] = MFMA(av[mi], bv[ni], acc[mi][ni]);
            }
        };

        STAGE(0, 0);
        __syncthreads();
        for (int t = 0; t < NT; ++t) {
            if (t + 1 < NT) STAGE((t + 1) & 1, t + 1);
            COMPUTE(t & 1);
            __syncthreads();
        }
        #pragma unroll
        for (int mi = 0; mi < 4; ++mi)
        #pragma unroll
        for (int ni = 0; ni < 2; ++ni) {
            const int col = bn + wc * 32 + ni * 16 + (lane & 15);
            const float bv = bias[col];
            #pragma unroll
            for (int jj = 0; jj < 4; ++jj) {
                const int row = bm + wr * 64 + mi * 16 + (lane >> 4) * 4 + jj;
                Cout[(size_t)row * ldc + col] = f2bf(fast_tanh(acc[mi][ni][jj] + bv));
            }
        }
    } else if (mode <= 2 && bid < 512) {       // ========== transpose 1024^2
        float (*tile)[65] = (float(*)[65])lds;
        const int idx = bid - 256;
        const int rb = (idx >> 4) * 64, cb = (idx & 15) * 64;
        for (int i = tid; i < 64 * 64; i += 256) {
            int r = i >> 6, c = i & 63;
            tile[r][c] = xsrc[(size_t)(rb + r) * 1024 + cb + c];
        }
        __syncthreads();
        for (int i = tid; i < 64 * 64; i += 256) {
            int c = i >> 6, r = i & 63;
            xdst[(size_t)(cb + c) * 1024 + rb + r] = f2bf(tile[r][c]);
        }
    } else if (mode == 2) {                    // ========== BW / bz
        const int lb = bid - 512;              // 0..512
        const int n = tid & 63, jc = tid >> 6;
        if (lb == 512) {
            float (*sh1)[64] = (float(*)[64])lds;
            float a = 0.f;
            for (int j = jc * 256; j < jc * 256 + 256; ++j)
                a = fmaf(bb4[j], W1[j * 64 + n], a);
            sh1[jc][n] = a;
            __syncthreads();
            if (tid < 64)
                bz[tid] = sh1[0][tid] + sh1[1][tid] + sh1[2][tid] + sh1[3][tid];
            return;
        }
        float (*sh)[2][64] = (float(*)[2][64])lds;     // [4][2][64]
        const int k0 = lb * 2;
        float a0 = 0.f, a1 = 0.f;
        for (int j = jc * 256; j < jc * 256 + 256; ++j) {
            float w = W1[j * 64 + n];
            a0 = fmaf(bw4[(size_t)k0 * 1024 + j], w, a0);
            a1 = fmaf(bw4[(size_t)(k0 + 1) * 1024 + j], w, a1);
        }
        sh[jc][0][n] = a0; sh[jc][1][n] = a1;
        __syncthreads();
        if (tid < 128) {
            int kk = tid >> 6, nn = tid & 63;
            float s = sh[0][kk][nn] + sh[1][kk][nn] + sh[2][kk][nn] + sh[3][kk][nn];
            BWt[(size_t)nn * 1024 + k0 + kk] = f2bf(s);
        }
    } else {                                   // ========== gather trunk (mode 3)
        float (*tile)[130] = (float(*)[130])lds;       // [32][130] = 16.6 KB
        const int idx = bid - 256;             // 0..515
        const int layer = idx / 258, pbi = idx % 258;
        u16* Btd = Btb + (size_t)layer * 128 * 8256;
        const int colbase = layer ? 16896 : 384, biasbase = layer ? 16768 : 256;
        const int pb = pbi * 32;
        for (int i = tid; i < 32 * 128; i += 256) {
            int p = pb + (i >> 7), n = i & 127;
            float v = (p < 8192)
                ? W2[(size_t)(p & 63) * LDP + colbase + (size_t)(p >> 6) * 128 + n]
                : W2[(size_t)(p - 8192) * LDP + biasbase + n];
            tile[i >> 7][n] = v;
        }
        __syncthreads();
        for (int i = tid; i < 32 * 128; i += 256) {
            int n = i >> 5, dp = i & 31;
            Btd[(size_t)n * 8256 + pb + dp] = f2bf(tile[dp][n]);
        }
    }
}

// ---------------------------------------------------------------------------
// z-GEMM: zc[kz][2048][64] = actB @ BWt^T partials, SK=8, 64x64 tile
// ---------------------------------------------------------------------------
__global__ __launch_bounds__(256, 2)
void zgemm(const u16* __restrict__ A, const u16* __restrict__ Bt,
           float* __restrict__ zc)
{
    __shared__ __align__(16) u16 As[2][64 * 32];
    __shared__ __align__(16) u16 Bs[2][64 * 32];
    const int tid = threadIdx.x, lane = tid & 63, wid = tid >> 6;
    const int wr = wid >> 1, wc = wid & 1;
    const int bm = blockIdx.y * 64, kz = blockIdx.z;
    const int t0 = kz * 4, nt = 4;
    const int arow = tid >> 2, ck = tid & 3;
    const u16* aSrc = A + (size_t)(bm + arow) * 1024 + (ck ^ (arow & 3)) * 8;
    const u16* bSrc = Bt + (size_t)arow * 1024 + (ck ^ (arow & 3)) * 8;
    f32x4 acc[2][2] = {};

    auto STAGE = [&](int buf, int t) {
        const int k0 = t << 5;
        gload_lds16(aSrc + k0, (char*)As[buf] + wid * 1024);
        gload_lds16(bSrc + k0, (char*)Bs[buf] + wid * 1024);
    };
    auto COMPUTE = [&](int buf) {
        s16x8 a[2];
        #pragma unroll
        for (int mi = 0; mi < 2; ++mi) {
            int row = wr * 32 + mi * 16 + (lane & 15);
            int s = (lane >> 4) ^ (row & 3);
            a[mi] = *(const s16x8*)&As[buf][row * 32 + s * 8];
        }
        #pragma unroll
        for (int ni = 0; ni < 2; ++ni) {
            int n = wc * 32 + ni * 16 + (lane & 15);
            int s = (lane >> 4) ^ (n & 3);
            s16x8 b = *(const s16x8*)&Bs[buf][n * 32 + s * 8];
            #pragma unroll
            for (int mi = 0; mi < 2; ++mi)
                acc[mi][ni] = MFMA(a[mi], b, acc[mi][ni]);
        }
    };

    STAGE(0, t0);
    __syncthreads();
    for (int t = 0; t < nt; ++t) {
        if (t + 1 < nt) STAGE((t + 1) & 1, t0 + t + 1);
        COMPUTE(t & 1);
        __syncthreads();
    }
    #pragma unroll
    for (int mi = 0; mi < 2; ++mi)
    #pragma unroll
    for (int ni = 0; ni < 2; ++ni) {
        const int col = wc * 32 + ni * 16 + (lane & 15);
        #pragma unroll
        for (int jj = 0; jj < 4; ++jj) {
            const int row = bm + wr * 32 + mi * 16 + (lane >> 4) * 4 + jj;
            zc[((size_t)kz * 2048 + row) * 64 + col] = acc[mi][ni][jj];
        }
    }
}

// ---------------------------------------------------------------------------
// Fused: reduce_z (+bz) -> z bf16 ; trunk L1 (K=64, VALU) -> h1 bf16
// ---------------------------------------------------------------------------
__global__ __launch_bounds__(256)
void z_l1_h1(const float* __restrict__ zc, const float* __restrict__ bz,
             const float* __restrict__ W2, const float* __restrict__ t,
             u16* __restrict__ z, u16* __restrict__ h1)
{
    __shared__ float zsh[16][64];
    const int rb = blockIdx.x * 16;
    #pragma unroll
    for (int ii = 0; ii < 4; ++ii) {
        int e = ii * 256 + threadIdx.x;
        int r = e >> 6, k = e & 63;
        size_t off = (size_t)(rb + r) * 64 + k;
        float s = bz[k];
        #pragma unroll
        for (int sk = 0; sk < 8; ++sk) s += zc[(size_t)sk * 2048 * 64 + off];
        zsh[r][k] = s;
        z[off] = f2bf(s);
    }
    __syncthreads();
    const int o = threadIdx.x & 127;
    const int rh = (threadIdx.x >> 7) * 8;
    float acc_a[8] = {}, acc_b[8] = {};
    for (int k = 0; k < 64; ++k) {
        float wa = W2[(size_t)k * LDP + o];
        float wb = W2[(size_t)k * LDP + 128 + o];
        #pragma unroll
        for (int r = 0; r < 8; ++r) {
            float zv = zsh[rh + r][k];
            acc_a[r] = fmaf(zv, wa, acc_a[r]);
            acc_b[r] = fmaf(zv, wb, acc_b[r]);
        }
    }
    #pragma unroll
    for (int r = 0; r < 8; ++r) {
        int b = rb + rh + r;
        h1[b * 128 + o] = f2bf(fast_tanh(t[b] * acc_b[r] + acc_a[r]));
    }
}

// ---------------------------------------------------------------------------
// Trunk GEMM: 512 threads / 8 waves (4Mx2N), 128x128 tile, SK=16.
// Grid (kz, m) — kz on x so same-kz blocks co-locate per XCD (Bt L2 reuse).
// A generated on the fly: p<8192: h[b,p>>6]*z[b,p&63]; else z[b,p-8192].
// ---------------------------------------------------------------------------
__global__ __launch_bounds__(512, 2)
void trunk128(const u16* __restrict__ h, const u16* __restrict__ z,
              const u16* __restrict__ Bt, float* __restrict__ Cp)
{
    constexpr int NT = 258, SKT = 16;
    __shared__ __align__(16) u16 As[2][128 * 32];
    __shared__ __align__(16) u16 Bs[2][128 * 32];
    const int tid = threadIdx.x, lane = tid & 63, wid = tid >> 6;
    const int wr = wid >> 1, wc = wid & 1;
    const int bm = blockIdx.y * 128, kz = blockIdx.x;   // kz fastest -> XCD locality
    const int t0 = (NT * kz) / SKT, t1 = (NT * (kz + 1)) / SKT;
    const int arow = tid >> 2, ck = tid & 3;
    const int b = bm + arow;
    const s16x8 zlo = *(const s16x8*)&z[b * 64 + ck * 8];
    const s16x8 zhi = *(const s16x8*)&z[b * 64 + 32 + ck * 8];
    const int slot = (ck ^ (arow & 3)) * 8;
    f32x4 acc[2][4] = {};

    auto STAGE = [&](int buf, int t) {
        const int p0 = t << 5;
        gload_lds16(Bt + (size_t)arow * 8256 + p0 + (ck ^ (arow & 3)) * 8,
                    (char*)Bs[buf] + wid * 1024);
        const s16x8 zv = (p0 & 32) ? zhi : zlo;
        u16 o8[8];
        if (p0 < 8192) {
            const float hf = bf2f(h[b * 128 + (p0 >> 6)]);
            #pragma unroll
            for (int j = 0; j < 8; ++j) o8[j] = f2bf(hf * bf2f((u16)zv[j]));
        } else {
            #pragma unroll
            for (int j = 0; j < 8; ++j) o8[j] = (u16)zv[j];
        }
        *(s16x8*)&As[buf][arow * 32 + slot] = *(s16x8*)o8;
    };
    auto COMPUTE = [&](int buf) {
        s16x8 av[2], bb[4];
        #pragma unroll
        for (int mi = 0; mi < 2; ++mi) {
            int row = wr * 32 + mi * 16 + (lane & 15);
            int s = (lane >> 4) ^ (row & 3);
            av[mi] = *(const s16x8*)&As[buf][row * 32 + s * 8];
        }
        #pragma unroll
        for (int ni = 0; ni < 4; ++ni) {
            int n = wc * 64 + ni * 16 + (lane & 15);
            int s = (lane >> 4) ^ (n & 3);
            bb[ni] = *(const s16x8*)&Bs[buf][n * 32 + s * 8];
        }
        #pragma unroll
        for (int mi = 0; mi < 2; ++mi)
        #pragma unroll
        for (int ni = 0; ni < 4; ++ni)
            acc[mi][ni] = MFMA(av[mi], bb[ni], acc[mi][ni]);
    };

    STAGE(0, t0);
    __syncthreads();
    const int nt = t1 - t0;
    for (int t = 0; t < nt; ++t) {
        if (t + 1 < nt) STAGE((t + 1) & 1, t0 + t + 1);
        COMPUTE(t & 1);
        __syncthreads();
    }

    #pragma unroll
    for (int mi = 0; mi < 2; ++mi)
    #pragma unroll
    for (int ni = 0; ni < 4; ++ni) {
        const int col = wc * 64 + ni * 16 + (lane & 15);
        #pragma unroll
        for (int jj = 0; jj < 4; ++jj) {
            const int row = bm + wr * 32 + mi * 16 + (lane >> 4) * 4 + jj;
            Cp[((size_t)kz * 2048 + row) * 128 + col] = acc[mi][ni][jj];
        }
    }
}

// ---------------------------------------------------------------------------
// reduce 16 split-K partials + tanh -> bf16 (float4-vectorized)
// ---------------------------------------------------------------------------
__global__ __launch_bounds__(256)
void reduce_tanh(const float* __restrict__ Cp, u16* __restrict__ hout) {
    const int i4 = (blockIdx.x * 256 + threadIdx.x) * 4;   // 2048*128 elems
    const size_t S = (size_t)2048 * 128;
    float4 s = make_float4(0.f, 0.f, 0.f, 0.f);
    #pragma unroll
    for (int k = 0; k < 16; ++k) {
        float4 v = *(const float4*)&Cp[(size_t)k * S + i4];
        s.x += v.x; s.y += v.y; s.z += v.z; s.w += v.w;
    }
    uint2 o;
    o.x = (u32)f2bf(fast_tanh(s.x)) | ((u32)f2bf(fast_tanh(s.y)) << 16);
    o.y = (u32)f2bf(fast_tanh(s.z)) | ((u32)f2bf(fast_tanh(s.w)) << 16);
    *(uint2*)&hout[i4] = o;
}

// layer-3 reduce+tanh fused with trunk L4 + final combine
__global__ __launch_bounds__(256)
void reduce_out(const float* __restrict__ Cp, const u16* __restrict__ z,
                const float* __restrict__ W2, const float* __restrict__ t,
                const float* __restrict__ u, float* __restrict__ out)
{
    __shared__ float sh[4][128];
    const int wv = threadIdx.x >> 6, l = threadIdx.x & 63;
    const int b = blockIdx.x * 4 + wv;
    const size_t S = (size_t)2048 * 128;
    #pragma unroll
    for (int e = l; e < 128; e += 64) {
        float s = 0.f;
        #pragma unroll
        for (int k = 0; k < 16; ++k) s += Cp[k * S + (size_t)b * 128 + e];
        sh[wv][e] = fast_tanh(s);
    }
    __syncthreads();
    const float* wrow = &W2[(size_t)l * LDP + 33280];
    float acc = wrow[0];
    #pragma unroll 8
    for (int i = 0; i < 128; ++i) acc = fmaf(sh[wv][i], wrow[1 + i], acc);
    float p = bf2f(z[b * 64 + l]) * acc;
    #pragma unroll
    for (int off = 32; off > 0; off >>= 1) p += __shfl_down(p, off);
    if (l == 0) out[b] = u[b * 128] + t[b] * p;
}

// ---------------------------------------------------------------------------
extern "C" void kernel_launch(void* const* d_in, const int* in_sizes, int n_in,
                              void* d_out, int out_size, void* d_ws, size_t ws_size,
                              hipStream_t stream)
{
    const float* t   = (const float*)d_in[0];
    const float* u   = (const float*)d_in[1];
    const float* bw0 = (const float*)d_in[2];
    const float* bb0 = (const float*)d_in[3];
    const float* bw1 = (const float*)d_in[4];
    const float* bb1 = (const float*)d_in[5];
    const float* bw2 = (const float*)d_in[6];
    const float* bb2 = (const float*)d_in[7];
    const float* bw3 = (const float*)d_in[8];
    const float* bb3 = (const float*)d_in[9];
    const float* bw4 = (const float*)d_in[10];
    const float* bb4 = (const float*)d_in[11];
    const float* W1  = (const float*)d_in[12];
    const float* W2  = (const float*)d_in[13];
    float* out = (float*)d_out;

    // ---- workspace layout (bytes) — same as r9/r11
    char* base = (char*)d_ws;
    u16*   bw1t = (u16*)(base);                  // 2 MB
    u16*   bw2t = (u16*)(base + 2097152);        // 2 MB
    u16*   bw3t = (u16*)(base + 4194304);        // 2 MB
    u16*   actA = (u16*)(base + 6291456);        // 4 MB
    u16*   actB = (u16*)(base + 10485760);       // 4 MB
    u16*   ubf  = (u16*)(base + 14680064);       // 512 KB
    u16*   bw0t = (u16*)(base + 15204352);       // 256 KB
    u16*   BWt  = (u16*)(base + 15499264);       // 128 KB
    float* bz   = (float*)(base + 15630336);     // 256 B
    u16*   z    = (u16*)(base + 16777216);       // 256 KB
    u16*   h1   = (u16*)(base + 17039360);       // 512 KB
    u16*   h2   = (u16*)(base + 17563648);       // 512 KB
    u16*   Bt   = (u16*)(base + 18087936);       // 4,227,072 (2 layers)
    // overlays:
    float* zc = (float*)(base);                  // 4 MB   (zgemm .. z_l1_h1)
    float* Cp = (float*)(base);                  // 16.78 MB (trunk partials)

    dim3 blk(256);
    // ---- prep0 (ubf + bw0t only)
    prep0<<<160, blk, 0, stream>>>(u, bw0, ubf, bw0t);

    // ---- branch MLP with horizontally-fused prep (128x64 tiles, BK=64)
    gemm_fused<<<512, blk, 0, stream>>>(                       // L0 + T(bw1)
        ubf, 128, bw0t, 128, bb0, actA, 1024, 128, 0,
        bw1, bw1t, bw4, bb4, W1, BWt, bz, W2, Bt);
    gemm_fused<<<512, blk, 0, stream>>>(                       // L1 + T(bw2)
        actA, 1024, bw1t, 1024, bb1, actB, 1024, 1024, 1,
        bw2, bw2t, bw4, bb4, W1, BWt, bz, W2, Bt);
    gemm_fused<<<1025, blk, 0, stream>>>(                      // L2 + T(bw3) + BW + bz
        actB, 1024, bw2t, 1024, bb2, actA, 1024, 1024, 2,
        bw3, bw3t, bw4, bb4, W1, BWt, bz, W2, Bt);
    gemm_fused<<<772, blk, 0, stream>>>(                       // L3 + gather Bt
        actA, 1024, bw3t, 1024, bb3, actB, 1024, 1024, 3,
        nullptr, nullptr, bw4, bb4, W1, BWt, bz, W2, Bt);
    // ---- z partials (SK=8)
    zgemm<<<dim3(1, 32, 8), blk, 0, stream>>>(actB, BWt, zc);
    // ---- fused reduce_z + trunk L1 + h1
    z_l1_h1<<<128, blk, 0, stream>>>(zc, bz, W2, t, z, h1);
    // ---- trunk layers 2,3 (128x128 tiles, 8 waves, split-K=16, kz-major grid)
    trunk128<<<dim3(16, 16), dim3(512), 0, stream>>>(h1, z, Bt, Cp);
    reduce_tanh<<<256, blk, 0, stream>>>(Cp, h2);
    trunk128<<<dim3(16, 16), dim3(512), 0, stream>>>(h2, z, Bt + (size_t)128 * 8256, Cp);
    // ---- layer-3 reduce + trunk L4 + combine
    reduce_out<<<512, blk, 0, stream>>>(Cp, z, W2, t, u, out);
}

// Round 13
// 139.436 us; speedup vs baseline: 1.0019x; 1.0019x over previous
//
#include <hip/hip_runtime.h>
#include <hip/hip_bf16.h>
#include <stdint.h>

typedef unsigned short u16;
typedef unsigned int   u32;
typedef short s16x8 __attribute__((ext_vector_type(8)));
typedef float f32x4 __attribute__((ext_vector_type(4)));

#define LDP 33409

__device__ __forceinline__ u16 f2bf(float f) {
    union { float f; u32 u; } v; v.f = f;
    u32 r = v.u + 0x7fffu + ((v.u >> 16) & 1u);
    return (u16)(r >> 16);
}
__device__ __forceinline__ float bf2f(u16 h) {
    union { u32 u; float f; } v; v.u = ((u32)h) << 16;
    return v.f;
}
__device__ __forceinline__ float fast_tanh(float x) {
    float e = __expf(2.0f * x);
    return 1.0f - 2.0f / (e + 1.0f);
}
__device__ __forceinline__ f32x4 MFMA(s16x8 a, s16x8 b, f32x4 c) {
    return __builtin_amdgcn_mfma_f32_16x16x32_bf16(a, b, c, 0, 0, 0);
}
__device__ __forceinline__ void gload_lds16(const void* g, void* l) {
    __builtin_amdgcn_global_load_lds(
        (const __attribute__((address_space(1))) u32*)(uintptr_t)g,
        (__attribute__((address_space(3))) u32*)(uintptr_t)l, 16, 0, 0);
}

// ---------------------------------------------------------------------------
// L0 fused: blocks [0,256): 128(M)x64(N) GEMM, BK=32, K=128, A/B staged
//   directly from f32 (u, bw0) with inline cvt (+ transpose for B).
// blocks [256,512): transpose bw1 (1024^2) -> bw1t[n][k]
// ---------------------------------------------------------------------------
__global__ __launch_bounds__(256, 2)
void gemm_l0(const float* __restrict__ u, const float* __restrict__ bw0,
             const float* __restrict__ bias, u16* __restrict__ Cout,
             const float* __restrict__ bw1, u16* __restrict__ bw1t)
{
    __shared__ __align__(16) char lds[24576];
    const int bid = blockIdx.x, tid = threadIdx.x;

    if (bid < 256) {                           // ========== GEMM 128x64, K=128
        u16 (*As)[128 * 32] = (u16(*)[128 * 32])lds;          // 2 x 8 KB
        u16 (*Bs)[64 * 32]  = (u16(*)[64 * 32])(lds + 16384); // 2 x 4 KB
        const int lane = tid & 63, wid = tid >> 6;
        const int wr = wid >> 1, wc = wid & 1;
        const int bn = (bid & 15) * 64, bm = (bid >> 4) * 128;
        f32x4 acc[4][2] = {};

        auto STAGE = [&](int buf, int t) {
            const int k0 = t << 5;
            #pragma unroll
            for (int r = 0; r < 2; ++r) {       // A: 128 rows x 32 k from u
                int idx = r * 256 + tid;
                int row = idx >> 2, ck = idx & 3;
                const float* src = u + (size_t)(bm + row) * 128 + k0 + ck * 8;
                float4 x = *(const float4*)src;
                float4 y = *(const float4*)(src + 4);
                u16 o8[8] = {f2bf(x.x), f2bf(x.y), f2bf(x.z), f2bf(x.w),
                             f2bf(y.x), f2bf(y.y), f2bf(y.z), f2bf(y.w)};
                *(s16x8*)&As[buf][row * 32 + ((ck ^ (row & 3)) << 3)] = *(s16x8*)o8;
            }
            {                                   // B: transpose bw0 tile
                int kk = tid >> 3, cg = tid & 7;
                const float* src = bw0 + (size_t)(k0 + kk) * 1024 + bn + cg * 8;
                float4 x = *(const float4*)src;
                float4 y = *(const float4*)(src + 4);
                float v[8] = {x.x, x.y, x.z, x.w, y.x, y.y, y.z, y.w};
                const int c = kk >> 3, e = kk & 7;
                #pragma unroll
                for (int j = 0; j < 8; ++j) {
                    int col = cg * 8 + j;
                    Bs[buf][col * 32 + ((c ^ (col & 3)) << 3) + e] = f2bf(v[j]);
                }
            }
        };
        auto COMPUTE = [&](int buf) {
            s16x8 av[4], bv[2];
            #pragma unroll
            for (int mi = 0; mi < 4; ++mi) {
                int row = wr * 64 + mi * 16 + (lane & 15);
                int s = (lane >> 4) ^ (row & 3);
                av[mi] = *(const s16x8*)&As[buf][row * 32 + s * 8];
            }
            #pragma unroll
            for (int ni = 0; ni < 2; ++ni) {
                int col = wc * 32 + ni * 16 + (lane & 15);
                int s = (lane >> 4) ^ (col & 3);
                bv[ni] = *(const s16x8*)&Bs[buf][col * 32 + s * 8];
            }
            #pragma unroll
            for (int mi = 0; mi < 4; ++mi)
            #pragma unroll
            for (int ni = 0; ni < 2; ++ni)
                acc[mi][ni] = MFMA(av[mi], bv[ni], acc[mi][ni]);
        };

        STAGE(0, 0);
        __syncthreads();
        #pragma unroll
        for (int t = 0; t < 4; ++t) {
            if (t + 1 < 4) STAGE((t + 1) & 1, t + 1);
            COMPUTE(t & 1);
            __syncthreads();
        }
        #pragma unroll
        for (int mi = 0; mi < 4; ++mi)
        #pragma unroll
        for (int ni = 0; ni < 2; ++ni) {
            const int col = bn + wc * 32 + ni * 16 + (lane & 15);
            const float bv = bias[col];
            #pragma unroll
            for (int jj = 0; jj < 4; ++jj) {
                const int row = bm + wr * 64 + mi * 16 + (lane >> 4) * 4 + jj;
                Cout[(size_t)row * 1024 + col] = f2bf(fast_tanh(acc[mi][ni][jj] + bv));
            }
        }
    } else {                                   // ========== transpose bw1
        float (*tile)[65] = (float(*)[65])lds;
        const int idx = bid - 256;
        const int rb = (idx >> 4) * 64, cb = (idx & 15) * 64;
        for (int i = tid; i < 64 * 64; i += 256) {
            int r = i >> 6, c = i & 63;
            tile[r][c] = bw1[(size_t)(rb + r) * 1024 + cb + c];
        }
        __syncthreads();
        for (int i = tid; i < 64 * 64; i += 256) {
            int c = i >> 6, r = i & 63;
            bw1t[(size_t)(cb + c) * 1024 + rb + r] = f2bf(tile[r][c]);
        }
    }
}

// ---------------------------------------------------------------------------
// Fused branch GEMM + horizontal prep (BK=32, 128x64 tile).
// blocks [0,256): GEMM; mode 1/2 [256,512): transpose; mode 2 [512,1025):
// BW/bz; mode 3 [256,772): gather trunk.
// ---------------------------------------------------------------------------
__global__ __launch_bounds__(256, 2)
void gemm_fused(const u16* __restrict__ A, int lda,
                const u16* __restrict__ Bt, int ldb,
                const float* __restrict__ bias,
                u16* __restrict__ Cout, int ldc, int K, int mode,
                const float* __restrict__ xsrc, u16* __restrict__ xdst,
                const float* __restrict__ bw4, const float* __restrict__ bb4,
                const float* __restrict__ W1, u16* __restrict__ BWt,
                float* __restrict__ bz,
                const float* __restrict__ W2, u16* __restrict__ Btb)
{
    __shared__ __align__(16) char lds[24576];
    const int bid = blockIdx.x, tid = threadIdx.x;

    if (bid < 256) {
        u16 (*As)[128 * 32] = (u16(*)[128 * 32])lds;
        u16 (*Bs)[64 * 32]  = (u16(*)[64 * 32])(lds + 16384);
        const int lane = tid & 63, wid = tid >> 6;
        const int wr = wid >> 1, wc = wid & 1;
        const int bn = (bid & 15) * 64, bm = (bid >> 4) * 128;
        const int NT = K >> 5;
        const int arow = tid >> 2, ck = tid & 3;
        const u16* aSrc = A + (size_t)(bm + arow) * lda + (ck ^ (arow & 3)) * 8;
        const u16* bSrc = Bt + (size_t)(bn + arow) * ldb + (ck ^ (arow & 3)) * 8;
        const size_t aHalf = (size_t)64 * lda;
        f32x4 acc[4][2] = {};

        auto STAGE = [&](int buf, int t) {
            const int k0 = t << 5;
            gload_lds16(aSrc + k0,         (char*)As[buf] + wid * 1024);
            gload_lds16(aSrc + aHalf + k0, (char*)As[buf] + 4096 + wid * 1024);
            gload_lds16(bSrc + k0,         (char*)Bs[buf] + wid * 1024);
        };
        auto COMPUTE = [&](int buf) {
            s16x8 av[4], bv[2];
            #pragma unroll
            for (int mi = 0; mi < 4; ++mi) {
                int row = wr * 64 + mi * 16 + (lane & 15);
                int s = (lane >> 4) ^ (row & 3);
                av[mi] = *(const s16x8*)&As[buf][row * 32 + s * 8];
            }
            #pragma unroll
            for (int ni = 0; ni < 2; ++ni) {
                int col = wc * 32 + ni * 16 + (lane & 15);
                int s = (lane >> 4) ^ (col & 3);
                bv[ni] = *(const s16x8*)&Bs[buf][col * 32 + s * 8];
            }
            #pragma unroll
            for (int mi = 0; mi < 4; ++mi)
            #pragma unroll
            for (int ni = 0; ni < 2; ++ni)
                acc[mi][ni] = MFMA(av[mi], bv[ni], acc[mi][ni]);
        };

        STAGE(0, 0);
        __syncthreads();
        for (int t = 0; t < NT; ++t) {
            if (t + 1 < NT) STAGE((t + 1) & 1, t + 1);
            COMPUTE(t & 1);
            __syncthreads();
        }
        #pragma unroll
        for (int mi = 0; mi < 4; ++mi)
        #pragma unroll
        for (int ni = 0; ni < 2; ++ni) {
            const int col = bn + wc * 32 + ni * 16 + (lane & 15);
            const float bv = bias[col];
            #pragma unroll
            for (int jj = 0; jj < 4; ++jj) {
                const int row = bm + wr * 64 + mi * 16 + (lane >> 4) * 4 + jj;
                Cout[(size_t)row * ldc + col] = f2bf(fast_tanh(acc[mi][ni][jj] + bv));
            }
        }
    } else if (mode <= 2 && bid < 512) {
        float (*tile)[65] = (float(*)[65])lds;
        const int idx = bid - 256;
        const int rb = (idx >> 4) * 64, cb = (idx & 15) * 64;
        for (int i = tid; i < 64 * 64; i += 256) {
            int r = i >> 6, c = i & 63;
            tile[r][c] = xsrc[(size_t)(rb + r) * 1024 + cb + c];
        }
        __syncthreads();
        for (int i = tid; i < 64 * 64; i += 256) {
            int c = i >> 6, r = i & 63;
            xdst[(size_t)(cb + c) * 1024 + rb + r] = f2bf(tile[r][c]);
        }
    } else if (mode == 2) {
        const int lb = bid - 512;
        const int n = tid & 63, jc = tid >> 6;
        if (lb == 512) {
            float (*sh1)[64] = (float(*)[64])lds;
            float a = 0.f;
            for (int j = jc * 256; j < jc * 256 + 256; ++j)
                a = fmaf(bb4[j], W1[j * 64 + n], a);
            sh1[jc][n] = a;
            __syncthreads();
            if (tid < 64)
                bz[tid] = sh1[0][tid] + sh1[1][tid] + sh1[2][tid] + sh1[3][tid];
            return;
        }
        float (*sh)[2][64] = (float(*)[2][64])lds;
        const int k0 = lb * 2;
        float a0 = 0.f, a1 = 0.f;
        for (int j = jc * 256; j < jc * 256 + 256; ++j) {
            float w = W1[j * 64 + n];
            a0 = fmaf(bw4[(size_t)k0 * 1024 + j], w, a0);
            a1 = fmaf(bw4[(size_t)(k0 + 1) * 1024 + j], w, a1);
        }
        sh[jc][0][n] = a0; sh[jc][1][n] = a1;
        __syncthreads();
        if (tid < 128) {
            int kk = tid >> 6, nn = tid & 63;
            float s = sh[0][kk][nn] + sh[1][kk][nn] + sh[2][kk][nn] + sh[3][kk][nn];
            BWt[(size_t)nn * 1024 + k0 + kk] = f2bf(s);
        }
    } else {
        float (*tile)[130] = (float(*)[130])lds;
        const int idx = bid - 256;
        const int layer = idx / 258, pbi = idx % 258;
        u16* Btd = Btb + (size_t)layer * 128 * 8256;
        const int colbase = layer ? 16896 : 384, biasbase = layer ? 16768 : 256;
        const int pb = pbi * 32;
        for (int i = tid; i < 32 * 128; i += 256) {
            int p = pb + (i >> 7), n = i & 127;
            float v = (p < 8192)
                ? W2[(size_t)(p & 63) * LDP + colbase + (size_t)(p >> 6) * 128 + n]
                : W2[(size_t)(p - 8192) * LDP + biasbase + n];
            tile[i >> 7][n] = v;
        }
        __syncthreads();
        for (int i = tid; i < 32 * 128; i += 256) {
            int n = i >> 5, dp = i & 31;
            Btd[(size_t)n * 8256 + pb + dp] = f2bf(tile[dp][n]);
        }
    }
}

// ---------------------------------------------------------------------------
__global__ __launch_bounds__(256, 2)
void zgemm(const u16* __restrict__ A, const u16* __restrict__ Bt,
           float* __restrict__ zc)
{
    __shared__ __align__(16) u16 As[2][64 * 32];
    __shared__ __align__(16) u16 Bs[2][64 * 32];
    const int tid = threadIdx.x, lane = tid & 63, wid = tid >> 6;
    const int wr = wid >> 1, wc = wid & 1;
    const int bm = blockIdx.y * 64, kz = blockIdx.z;
    const int t0 = kz * 4, nt = 4;
    const int arow = tid >> 2, ck = tid & 3;
    const u16* aSrc = A + (size_t)(bm + arow) * 1024 + (ck ^ (arow & 3)) * 8;
    const u16* bSrc = Bt + (size_t)arow * 1024 + (ck ^ (arow & 3)) * 8;
    f32x4 acc[2][2] = {};

    auto STAGE = [&](int buf, int t) {
        const int k0 = t << 5;
        gload_lds16(aSrc + k0, (char*)As[buf] + wid * 1024);
        gload_lds16(bSrc + k0, (char*)Bs[buf] + wid * 1024);
    };
    auto COMPUTE = [&](int buf) {
        s16x8 a[2];
        #pragma unroll
        for (int mi = 0; mi < 2; ++mi) {
            int row = wr * 32 + mi * 16 + (lane & 15);
            int s = (lane >> 4) ^ (row & 3);
            a[mi] = *(const s16x8*)&As[buf][row * 32 + s * 8];
        }
        #pragma unroll
        for (int ni = 0; ni < 2; ++ni) {
            int n = wc * 32 + ni * 16 + (lane & 15);
            int s = (lane >> 4) ^ (n & 3);
            s16x8 b = *(const s16x8*)&Bs[buf][n * 32 + s * 8];
            #pragma unroll
            for (int mi = 0; mi < 2; ++mi)
                acc[mi][ni] = MFMA(a[mi], b, acc[mi][ni]);
        }
    };

    STAGE(0, t0);
    __syncthreads();
    for (int t = 0; t < nt; ++t) {
        if (t + 1 < nt) STAGE((t + 1) & 1, t0 + t + 1);
        COMPUTE(t & 1);
        __syncthreads();
    }
    #pragma unroll
    for (int mi = 0; mi < 2; ++mi)
    #pragma unroll
    for (int ni = 0; ni < 2; ++ni) {
        const int col = wc * 32 + ni * 16 + (lane & 15);
        #pragma unroll
        for (int jj = 0; jj < 4; ++jj) {
            const int row = bm + wr * 32 + mi * 16 + (lane >> 4) * 4 + jj;
            zc[((size_t)kz * 2048 + row) * 64 + col] = acc[mi][ni][jj];
        }
    }
}

// ---------------------------------------------------------------------------
__global__ __launch_bounds__(256)
void z_l1_h1(const float* __restrict__ zc, const float* __restrict__ bz,
             const float* __restrict__ W2, const float* __restrict__ t,
             u16* __restrict__ z, u16* __restrict__ h1)
{
    __shared__ float zsh[16][64];
    const int rb = blockIdx.x * 16;
    #pragma unroll
    for (int ii = 0; ii < 4; ++ii) {
        int e = ii * 256 + threadIdx.x;
        int r = e >> 6, k = e & 63;
        size_t off = (size_t)(rb + r) * 64 + k;
        float s = bz[k];
        #pragma unroll
        for (int sk = 0; sk < 8; ++sk) s += zc[(size_t)sk * 2048 * 64 + off];
        zsh[r][k] = s;
        z[off] = f2bf(s);
    }
    __syncthreads();
    const int o = threadIdx.x & 127;
    const int rh = (threadIdx.x >> 7) * 8;
    float acc_a[8] = {}, acc_b[8] = {};
    for (int k = 0; k < 64; ++k) {
        float wa = W2[(size_t)k * LDP + o];
        float wb = W2[(size_t)k * LDP + 128 + o];
        #pragma unroll
        for (int r = 0; r < 8; ++r) {
            float zv = zsh[rh + r][k];
            acc_a[r] = fmaf(zv, wa, acc_a[r]);
            acc_b[r] = fmaf(zv, wb, acc_b[r]);
        }
    }
    #pragma unroll
    for (int r = 0; r < 8; ++r) {
        int b = rb + rh + r;
        h1[b * 128 + o] = f2bf(fast_tanh(t[b] * acc_b[r] + acc_a[r]));
    }
}

// ---------------------------------------------------------------------------
__global__ __launch_bounds__(512, 2)
void trunk128(const u16* __restrict__ h, const u16* __restrict__ z,
              const u16* __restrict__ Bt, float* __restrict__ Cp)
{
    constexpr int NT = 258, SKT = 16;
    __shared__ __align__(16) u16 As[2][128 * 32];
    __shared__ __align__(16) u16 Bs[2][128 * 32];
    const int tid = threadIdx.x, lane = tid & 63, wid = tid >> 6;
    const int wr = wid >> 1, wc = wid & 1;
    const int bm = blockIdx.y * 128, kz = blockIdx.x;   // kz-major: XCD locality
    const int t0 = (NT * kz) / SKT, t1 = (NT * (kz + 1)) / SKT;
    const int arow = tid >> 2, ck = tid & 3;
    const int b = bm + arow;
    const s16x8 zlo = *(const s16x8*)&z[b * 64 + ck * 8];
    const s16x8 zhi = *(const s16x8*)&z[b * 64 + 32 + ck * 8];
    const int slot = (ck ^ (arow & 3)) * 8;
    f32x4 acc[2][4] = {};

    auto STAGE = [&](int buf, int t) {
        const int p0 = t << 5;
        gload_lds16(Bt + (size_t)arow * 8256 + p0 + (ck ^ (arow & 3)) * 8,
                    (char*)Bs[buf] + wid * 1024);
        const s16x8 zv = (p0 & 32) ? zhi : zlo;
        u16 o8[8];
        if (p0 < 8192) {
            const float hf = bf2f(h[b * 128 + (p0 >> 6)]);
            #pragma unroll
            for (int j = 0; j < 8; ++j) o8[j] = f2bf(hf * bf2f((u16)zv[j]));
        } else {
            #pragma unroll
            for (int j = 0; j < 8; ++j) o8[j] = (u16)zv[j];
        }
        *(s16x8*)&As[buf][arow * 32 + slot] = *(s16x8*)o8;
    };
    auto COMPUTE = [&](int buf) {
        s16x8 av[2], bb[4];
        #pragma unroll
        for (int mi = 0; mi < 2; ++mi) {
            int row = wr * 32 + mi * 16 + (lane & 15);
            int s = (lane >> 4) ^ (row & 3);
            av[mi] = *(const s16x8*)&As[buf][row * 32 + s * 8];
        }
        #pragma unroll
        for (int ni = 0; ni < 4; ++ni) {
            int n = wc * 64 + ni * 16 + (lane & 15);
            int s = (lane >> 4) ^ (n & 3);
            bb[ni] = *(const s16x8*)&Bs[buf][n * 32 + s * 8];
        }
        #pragma unroll
        for (int mi = 0; mi < 2; ++mi)
        #pragma unroll
        for (int ni = 0; ni < 4; ++ni)
            acc[mi][ni] = MFMA(av[mi], bb[ni], acc[mi][ni]);
    };

    STAGE(0, t0);
    __syncthreads();
    const int nt = t1 - t0;
    for (int t = 0; t < nt; ++t) {
        if (t + 1 < nt) STAGE((t + 1) & 1, t0 + t + 1);
        COMPUTE(t & 1);
        __syncthreads();
    }

    #pragma unroll
    for (int mi = 0; mi < 2; ++mi)
    #pragma unroll
    for (int ni = 0; ni < 4; ++ni) {
        const int col = wc * 64 + ni * 16 + (lane & 15);
        #pragma unroll
        for (int jj = 0; jj < 4; ++jj) {
            const int row = bm + wr * 32 + mi * 16 + (lane >> 4) * 4 + jj;
            Cp[((size_t)kz * 2048 + row) * 128 + col] = acc[mi][ni][jj];
        }
    }
}

// ---------------------------------------------------------------------------
__global__ __launch_bounds__(256)
void reduce_tanh(const float* __restrict__ Cp, u16* __restrict__ hout) {
    const int i4 = (blockIdx.x * 256 + threadIdx.x) * 4;
    const size_t S = (size_t)2048 * 128;
    float4 s = make_float4(0.f, 0.f, 0.f, 0.f);
    #pragma unroll
    for (int k = 0; k < 16; ++k) {
        float4 v = *(const float4*)&Cp[(size_t)k * S + i4];
        s.x += v.x; s.y += v.y; s.z += v.z; s.w += v.w;
    }
    uint2 o;
    o.x = (u32)f2bf(fast_tanh(s.x)) | ((u32)f2bf(fast_tanh(s.y)) << 16);
    o.y = (u32)f2bf(fast_tanh(s.z)) | ((u32)f2bf(fast_tanh(s.w)) << 16);
    *(uint2*)&hout[i4] = o;
}

__global__ __launch_bounds__(256)
void reduce_out(const float* __restrict__ Cp, const u16* __restrict__ z,
                const float* __restrict__ W2, const float* __restrict__ t,
                const float* __restrict__ u, float* __restrict__ out)
{
    __shared__ float sh[4][128];
    const int wv = threadIdx.x >> 6, l = threadIdx.x & 63;
    const int b = blockIdx.x * 4 + wv;
    const size_t S = (size_t)2048 * 128;
    #pragma unroll
    for (int e = l; e < 128; e += 64) {
        float s = 0.f;
        #pragma unroll
        for (int k = 0; k < 16; ++k) s += Cp[k * S + (size_t)b * 128 + e];
        sh[wv][e] = fast_tanh(s);
    }
    __syncthreads();
    const float* wrow = &W2[(size_t)l * LDP + 33280];
    float acc = wrow[0];
    #pragma unroll 8
    for (int i = 0; i < 128; ++i) acc = fmaf(sh[wv][i], wrow[1 + i], acc);
    float p = bf2f(z[b * 64 + l]) * acc;
    #pragma unroll
    for (int off = 32; off > 0; off >>= 1) p += __shfl_down(p, off);
    if (l == 0) out[b] = u[b * 128] + t[b] * p;
}

// ---------------------------------------------------------------------------
extern "C" void kernel_launch(void* const* d_in, const int* in_sizes, int n_in,
                              void* d_out, int out_size, void* d_ws, size_t ws_size,
                              hipStream_t stream)
{
    const float* t   = (const float*)d_in[0];
    const float* u   = (const float*)d_in[1];
    const float* bw0 = (const float*)d_in[2];
    const float* bb0 = (const float*)d_in[3];
    const float* bw1 = (const float*)d_in[4];
    const float* bb1 = (const float*)d_in[5];
    const float* bw2 = (const float*)d_in[6];
    const float* bb2 = (const float*)d_in[7];
    const float* bw3 = (const float*)d_in[8];
    const float* bb3 = (const float*)d_in[9];
    const float* bw4 = (const float*)d_in[10];
    const float* bb4 = (const float*)d_in[11];
    const float* W1  = (const float*)d_in[12];
    const float* W2  = (const float*)d_in[13];
    float* out = (float*)d_out;

    char* base = (char*)d_ws;
    u16*   bw1t = (u16*)(base);                  // 2 MB
    u16*   bw2t = (u16*)(base + 2097152);        // 2 MB
    u16*   bw3t = (u16*)(base + 4194304);        // 2 MB
    u16*   actA = (u16*)(base + 6291456);        // 4 MB
    u16*   actB = (u16*)(base + 10485760);       // 4 MB
    u16*   BWt  = (u16*)(base + 15499264);       // 128 KB
    float* bz   = (float*)(base + 15630336);     // 256 B
    u16*   z    = (u16*)(base + 16777216);       // 256 KB
    u16*   h1   = (u16*)(base + 17039360);       // 512 KB
    u16*   h2   = (u16*)(base + 17563648);       // 512 KB
    u16*   Bt   = (u16*)(base + 18087936);       // 4,227,072 (2 layers)
    float* zc = (float*)(base);                  // overlay: 4 MB
    float* Cp = (float*)(base);                  // overlay: 16.78 MB

    dim3 blk(256);
    // ---- L0 (inline f32 staging) + T(bw1)
    gemm_l0<<<512, blk, 0, stream>>>(u, bw0, bb0, actA, bw1, bw1t);
    // ---- branch L1-L3 with horizontal prep
    gemm_fused<<<512, blk, 0, stream>>>(                       // L1 + T(bw2)
        actA, 1024, bw1t, 1024, bb1, actB, 1024, 1024, 1,
        bw2, bw2t, bw4, bb4, W1, BWt, bz, W2, Bt);
    gemm_fused<<<1025, blk, 0, stream>>>(                      // L2 + T(bw3) + BW + bz
        actB, 1024, bw2t, 1024, bb2, actA, 1024, 1024, 2,
        bw3, bw3t, bw4, bb4, W1, BWt, bz, W2, Bt);
    gemm_fused<<<772, blk, 0, stream>>>(                       // L3 + gather Bt
        actA, 1024, bw3t, 1024, bb3, actB, 1024, 1024, 3,
        nullptr, nullptr, bw4, bb4, W1, BWt, bz, W2, Bt);
    // ---- z partials (SK=8)
    zgemm<<<dim3(1, 32, 8), blk, 0, stream>>>(actB, BWt, zc);
    // ---- fused reduce_z + trunk L1 + h1
    z_l1_h1<<<128, blk, 0, stream>>>(zc, bz, W2, t, z, h1);
    // ---- trunk layers 2,3
    trunk128<<<dim3(16, 16), dim3(512), 0, stream>>>(h1, z, Bt, Cp);
    reduce_tanh<<<256, blk, 0, stream>>>(Cp, h2);
    trunk128<<<dim3(16, 16), dim3(512), 0, stream>>>(h2, z, Bt + (size_t)128 * 8256, Cp);
    // ---- layer-3 reduce + trunk L4 + combine
    reduce_out<<<512, blk, 0, stream>>>(Cp, z, W2, t, u, out);
}

// Round 14
// 137.700 us; speedup vs baseline: 1.0145x; 1.0126x over previous
//
#include <hip/hip_runtime.h>
#include <hip/hip_bf16.h>
#include <stdint.h>

typedef unsigned short u16;
typedef unsigned int   u32;
typedef short s16x8 __attribute__((ext_vector_type(8)));
typedef float f32x4 __attribute__((ext_vector_type(4)));

#define LDP 33409

__device__ __forceinline__ u16 f2bf(float f) {
    union { float f; u32 u; } v; v.f = f;
    u32 r = v.u + 0x7fffu + ((v.u >> 16) & 1u);
    return (u16)(r >> 16);
}
__device__ __forceinline__ float bf2f(u16 h) {
    union { u32 u; float f; } v; v.u = ((u32)h) << 16;
    return v.f;
}
__device__ __forceinline__ float fast_tanh(float x) {
    float e = __expf(2.0f * x);
    return 1.0f - 2.0f / (e + 1.0f);
}
__device__ __forceinline__ f32x4 MFMA(s16x8 a, s16x8 b, f32x4 c) {
    return __builtin_amdgcn_mfma_f32_16x16x32_bf16(a, b, c, 0, 0, 0);
}
__device__ __forceinline__ void gload_lds16(const void* g, void* l) {
    __builtin_amdgcn_global_load_lds(
        (const __attribute__((address_space(1))) u32*)(uintptr_t)g,
        (__attribute__((address_space(3))) u32*)(uintptr_t)l, 16, 0, 0);
}

// ---------------------------------------------------------------------------
// L0 fused: blocks [0,256): 128(M)x64(N) GEMM, BK=32, K=128, A/B staged
//   directly from f32 (u, bw0) with inline cvt (+ transpose for B).
// blocks [256,512): transpose bw1 (1024^2) -> bw1t[n][k]
// blocks [512,1028): gather trunk Bt[layer][n][p] (32-row tiles)
// ---------------------------------------------------------------------------
__global__ __launch_bounds__(256, 2)
void gemm_l0(const float* __restrict__ u, const float* __restrict__ bw0,
             const float* __restrict__ bias, u16* __restrict__ Cout,
             const float* __restrict__ bw1, u16* __restrict__ bw1t,
             const float* __restrict__ W2, u16* __restrict__ Btb)
{
    __shared__ __align__(16) char lds[24576];
    const int bid = blockIdx.x, tid = threadIdx.x;

    if (bid < 256) {                           // ========== GEMM 128x64, K=128
        u16 (*As)[128 * 32] = (u16(*)[128 * 32])lds;          // 2 x 8 KB
        u16 (*Bs)[64 * 32]  = (u16(*)[64 * 32])(lds + 16384); // 2 x 4 KB
        const int lane = tid & 63, wid = tid >> 6;
        const int wr = wid >> 1, wc = wid & 1;
        const int bn = (bid & 15) * 64, bm = (bid >> 4) * 128;
        f32x4 acc[4][2] = {};

        auto STAGE = [&](int buf, int t) {
            const int k0 = t << 5;
            #pragma unroll
            for (int r = 0; r < 2; ++r) {       // A: 128 rows x 32 k from u
                int idx = r * 256 + tid;
                int row = idx >> 2, ck = idx & 3;
                const float* src = u + (size_t)(bm + row) * 128 + k0 + ck * 8;
                float4 x = *(const float4*)src;
                float4 y = *(const float4*)(src + 4);
                u16 o8[8] = {f2bf(x.x), f2bf(x.y), f2bf(x.z), f2bf(x.w),
                             f2bf(y.x), f2bf(y.y), f2bf(y.z), f2bf(y.w)};
                *(s16x8*)&As[buf][row * 32 + ((ck ^ (row & 3)) << 3)] = *(s16x8*)o8;
            }
            {                                   // B: transpose bw0 tile
                int kk = tid >> 3, cg = tid & 7;
                const float* src = bw0 + (size_t)(k0 + kk) * 1024 + bn + cg * 8;
                float4 x = *(const float4*)src;
                float4 y = *(const float4*)(src + 4);
                float v[8] = {x.x, x.y, x.z, x.w, y.x, y.y, y.z, y.w};
                const int c = kk >> 3, e = kk & 7;
                #pragma unroll
                for (int j = 0; j < 8; ++j) {
                    int col = cg * 8 + j;
                    Bs[buf][col * 32 + ((c ^ (col & 3)) << 3) + e] = f2bf(v[j]);
                }
            }
        };
        auto COMPUTE = [&](int buf) {
            s16x8 av[4], bv[2];
            #pragma unroll
            for (int mi = 0; mi < 4; ++mi) {
                int row = wr * 64 + mi * 16 + (lane & 15);
                int s = (lane >> 4) ^ (row & 3);
                av[mi] = *(const s16x8*)&As[buf][row * 32 + s * 8];
            }
            #pragma unroll
            for (int ni = 0; ni < 2; ++ni) {
                int col = wc * 32 + ni * 16 + (lane & 15);
                int s = (lane >> 4) ^ (col & 3);
                bv[ni] = *(const s16x8*)&Bs[buf][col * 32 + s * 8];
            }
            #pragma unroll
            for (int mi = 0; mi < 4; ++mi)
            #pragma unroll
            for (int ni = 0; ni < 2; ++ni)
                acc[mi][ni] = MFMA(av[mi], bv[ni], acc[mi][ni]);
        };

        STAGE(0, 0);
        __syncthreads();
        #pragma unroll
        for (int t = 0; t < 4; ++t) {
            if (t + 1 < 4) STAGE((t + 1) & 1, t + 1);
            COMPUTE(t & 1);
            __syncthreads();
        }
        #pragma unroll
        for (int mi = 0; mi < 4; ++mi)
        #pragma unroll
        for (int ni = 0; ni < 2; ++ni) {
            const int col = bn + wc * 32 + ni * 16 + (lane & 15);
            const float bv = bias[col];
            #pragma unroll
            for (int jj = 0; jj < 4; ++jj) {
                const int row = bm + wr * 64 + mi * 16 + (lane >> 4) * 4 + jj;
                Cout[(size_t)row * 1024 + col] = f2bf(fast_tanh(acc[mi][ni][jj] + bv));
            }
        }
    } else if (bid < 512) {                    // ========== transpose bw1
        float (*tile)[65] = (float(*)[65])lds;
        const int idx = bid - 256;
        const int rb = (idx >> 4) * 64, cb = (idx & 15) * 64;
        for (int i = tid; i < 64 * 64; i += 256) {
            int r = i >> 6, c = i & 63;
            tile[r][c] = bw1[(size_t)(rb + r) * 1024 + cb + c];
        }
        __syncthreads();
        for (int i = tid; i < 64 * 64; i += 256) {
            int c = i >> 6, r = i & 63;
            bw1t[(size_t)(cb + c) * 1024 + rb + r] = f2bf(tile[r][c]);
        }
    } else {                                   // ========== gather trunk
        float (*tile)[130] = (float(*)[130])lds;       // [32][130] = 16.6 KB
        const int idx = bid - 512;             // 0..515
        const int layer = idx / 258, pbi = idx % 258;
        u16* Btd = Btb + (size_t)layer * 128 * 8256;
        const int colbase = layer ? 16896 : 384, biasbase = layer ? 16768 : 256;
        const int pb = pbi * 32;
        for (int i = tid; i < 32 * 128; i += 256) {
            int p = pb + (i >> 7), n = i & 127;
            float v = (p < 8192)
                ? W2[(size_t)(p & 63) * LDP + colbase + (size_t)(p >> 6) * 128 + n]
                : W2[(size_t)(p - 8192) * LDP + biasbase + n];
            tile[i >> 7][n] = v;
        }
        __syncthreads();
        for (int i = tid; i < 32 * 128; i += 256) {
            int n = i >> 5, dp = i & 31;
            Btd[(size_t)n * 8256 + pb + dp] = f2bf(tile[dp][n]);
        }
    }
}

// ---------------------------------------------------------------------------
// Fused branch GEMM + horizontal prep (BK=32, 128x64 tile).
// blocks [0,256): GEMM; mode 1/2 [256,512): transpose; mode 2 [512,1025): BW/bz.
// ---------------------------------------------------------------------------
__global__ __launch_bounds__(256, 2)
void gemm_fused(const u16* __restrict__ A, int lda,
                const u16* __restrict__ Bt, int ldb,
                const float* __restrict__ bias,
                u16* __restrict__ Cout, int ldc, int K, int mode,
                const float* __restrict__ xsrc, u16* __restrict__ xdst,
                const float* __restrict__ bw4, const float* __restrict__ bb4,
                const float* __restrict__ W1, u16* __restrict__ BWt,
                float* __restrict__ bz)
{
    __shared__ __align__(16) char lds[24576];
    const int bid = blockIdx.x, tid = threadIdx.x;

    if (bid < 256) {
        u16 (*As)[128 * 32] = (u16(*)[128 * 32])lds;
        u16 (*Bs)[64 * 32]  = (u16(*)[64 * 32])(lds + 16384);
        const int lane = tid & 63, wid = tid >> 6;
        const int wr = wid >> 1, wc = wid & 1;
        const int bn = (bid & 15) * 64, bm = (bid >> 4) * 128;
        const int NT = K >> 5;
        const int arow = tid >> 2, ck = tid & 3;
        const u16* aSrc = A + (size_t)(bm + arow) * lda + (ck ^ (arow & 3)) * 8;
        const u16* bSrc = Bt + (size_t)(bn + arow) * ldb + (ck ^ (arow & 3)) * 8;
        const size_t aHalf = (size_t)64 * lda;
        f32x4 acc[4][2] = {};

        auto STAGE = [&](int buf, int t) {
            const int k0 = t << 5;
            gload_lds16(aSrc + k0,         (char*)As[buf] + wid * 1024);
            gload_lds16(aSrc + aHalf + k0, (char*)As[buf] + 4096 + wid * 1024);
            gload_lds16(bSrc + k0,         (char*)Bs[buf] + wid * 1024);
        };
        auto COMPUTE = [&](int buf) {
            s16x8 av[4], bv[2];
            #pragma unroll
            for (int mi = 0; mi < 4; ++mi) {
                int row = wr * 64 + mi * 16 + (lane & 15);
                int s = (lane >> 4) ^ (row & 3);
                av[mi] = *(const s16x8*)&As[buf][row * 32 + s * 8];
            }
            #pragma unroll
            for (int ni = 0; ni < 2; ++ni) {
                int col = wc * 32 + ni * 16 + (lane & 15);
                int s = (lane >> 4) ^ (col & 3);
                bv[ni] = *(const s16x8*)&Bs[buf][col * 32 + s * 8];
            }
            #pragma unroll
            for (int mi = 0; mi < 4; ++mi)
            #pragma unroll
            for (int ni = 0; ni < 2; ++ni)
                acc[mi][ni] = MFMA(av[mi], bv[ni], acc[mi][ni]);
        };

        STAGE(0, 0);
        __syncthreads();
        for (int t = 0; t < NT; ++t) {
            if (t + 1 < NT) STAGE((t + 1) & 1, t + 1);
            COMPUTE(t & 1);
            __syncthreads();
        }
        #pragma unroll
        for (int mi = 0; mi < 4; ++mi)
        #pragma unroll
        for (int ni = 0; ni < 2; ++ni) {
            const int col = bn + wc * 32 + ni * 16 + (lane & 15);
            const float bv = bias[col];
            #pragma unroll
            for (int jj = 0; jj < 4; ++jj) {
                const int row = bm + wr * 64 + mi * 16 + (lane >> 4) * 4 + jj;
                Cout[(size_t)row * ldc + col] = f2bf(fast_tanh(acc[mi][ni][jj] + bv));
            }
        }
    } else if (mode <= 2 && bid < 512) {
        float (*tile)[65] = (float(*)[65])lds;
        const int idx = bid - 256;
        const int rb = (idx >> 4) * 64, cb = (idx & 15) * 64;
        for (int i = tid; i < 64 * 64; i += 256) {
            int r = i >> 6, c = i & 63;
            tile[r][c] = xsrc[(size_t)(rb + r) * 1024 + cb + c];
        }
        __syncthreads();
        for (int i = tid; i < 64 * 64; i += 256) {
            int c = i >> 6, r = i & 63;
            xdst[(size_t)(cb + c) * 1024 + rb + r] = f2bf(tile[r][c]);
        }
    } else if (mode == 2) {
        const int lb = bid - 512;
        const int n = tid & 63, jc = tid >> 6;
        if (lb == 512) {
            float (*sh1)[64] = (float(*)[64])lds;
            float a = 0.f;
            for (int j = jc * 256; j < jc * 256 + 256; ++j)
                a = fmaf(bb4[j], W1[j * 64 + n], a);
            sh1[jc][n] = a;
            __syncthreads();
            if (tid < 64)
                bz[tid] = sh1[0][tid] + sh1[1][tid] + sh1[2][tid] + sh1[3][tid];
            return;
        }
        float (*sh)[2][64] = (float(*)[2][64])lds;
        const int k0 = lb * 2;
        float a0 = 0.f, a1 = 0.f;
        for (int j = jc * 256; j < jc * 256 + 256; ++j) {
            float w = W1[j * 64 + n];
            a0 = fmaf(bw4[(size_t)k0 * 1024 + j], w, a0);
            a1 = fmaf(bw4[(size_t)(k0 + 1) * 1024 + j], w, a1);
        }
        sh[jc][0][n] = a0; sh[jc][1][n] = a1;
        __syncthreads();
        if (tid < 128) {
            int kk = tid >> 6, nn = tid & 63;
            float s = sh[0][kk][nn] + sh[1][kk][nn] + sh[2][kk][nn] + sh[3][kk][nn];
            BWt[(size_t)nn * 1024 + k0 + kk] = f2bf(s);
        }
    }
}

// ---------------------------------------------------------------------------
// L3 pure GEMM: 64x64 tile, grid (16,32) = 512 blocks (2/CU).
// ---------------------------------------------------------------------------
__global__ __launch_bounds__(256, 2)
void gemm_plain(const u16* __restrict__ A, const u16* __restrict__ Bt,
                const float* __restrict__ bias, u16* __restrict__ Cout)
{
    __shared__ __align__(16) u16 As[2][64 * 32];
    __shared__ __align__(16) u16 Bs[2][64 * 32];
    const int tid = threadIdx.x, lane = tid & 63, wid = tid >> 6;
    const int wr = wid >> 1, wc = wid & 1;
    const int bn = blockIdx.x * 64, bm = blockIdx.y * 64;
    const int arow = tid >> 2, ck = tid & 3;
    const u16* aSrc = A + (size_t)(bm + arow) * 1024 + (ck ^ (arow & 3)) * 8;
    const u16* bSrc = Bt + (size_t)(bn + arow) * 1024 + (ck ^ (arow & 3)) * 8;
    f32x4 acc[2][2] = {};

    auto STAGE = [&](int buf, int t) {
        const int k0 = t << 5;
        gload_lds16(aSrc + k0, (char*)As[buf] + wid * 1024);
        gload_lds16(bSrc + k0, (char*)Bs[buf] + wid * 1024);
    };
    auto COMPUTE = [&](int buf) {
        s16x8 a[2], b[2];
        #pragma unroll
        for (int mi = 0; mi < 2; ++mi) {
            int row = wr * 32 + mi * 16 + (lane & 15);
            int s = (lane >> 4) ^ (row & 3);
            a[mi] = *(const s16x8*)&As[buf][row * 32 + s * 8];
        }
        #pragma unroll
        for (int ni = 0; ni < 2; ++ni) {
            int n = wc * 32 + ni * 16 + (lane & 15);
            int s = (lane >> 4) ^ (n & 3);
            b[ni] = *(const s16x8*)&Bs[buf][n * 32 + s * 8];
        }
        #pragma unroll
        for (int mi = 0; mi < 2; ++mi)
        #pragma unroll
        for (int ni = 0; ni < 2; ++ni)
            acc[mi][ni] = MFMA(a[mi], b[ni], acc[mi][ni]);
    };

    STAGE(0, 0);
    __syncthreads();
    for (int t = 0; t < 32; ++t) {
        if (t + 1 < 32) STAGE((t + 1) & 1, t + 1);
        COMPUTE(t & 1);
        __syncthreads();
    }
    #pragma unroll
    for (int mi = 0; mi < 2; ++mi)
    #pragma unroll
    for (int ni = 0; ni < 2; ++ni) {
        const int col = bn + wc * 32 + ni * 16 + (lane & 15);
        const float bv = bias[col];
        #pragma unroll
        for (int jj = 0; jj < 4; ++jj) {
            const int row = bm + wr * 32 + mi * 16 + (lane >> 4) * 4 + jj;
            Cout[(size_t)row * 1024 + col] = f2bf(fast_tanh(acc[mi][ni][jj] + bv));
        }
    }
}

// ---------------------------------------------------------------------------
// Fused z + trunk L1 + h1: one dispatch.
// Block = 16 rows x full N=64, full K=1024. 4 waves, wave w owns N-slice w*16.
// Epilogue: +bz -> write z bf16 -> zsh (f32 LDS) -> trunk-L1 VALU -> h1.
// ---------------------------------------------------------------------------
__global__ __launch_bounds__(256)
void z_h1(const u16* __restrict__ A, const u16* __restrict__ Bt,
          const float* __restrict__ bz, const float* __restrict__ W2,
          const float* __restrict__ t, u16* __restrict__ z,
          u16* __restrict__ h1)
{
    __shared__ __align__(16) u16 As[2][16 * 32];
    __shared__ __align__(16) u16 Bs[2][64 * 32];
    __shared__ float zsh[16][64];
    const int tid = threadIdx.x, lane = tid & 63, wid = tid >> 6;
    const int rb = blockIdx.x * 16;
    const int brow = tid >> 2, bck = tid & 3;
    const u16* bSrc = Bt + (size_t)brow * 1024 + (bck ^ (brow & 3)) * 8;
    const int aRow = lane >> 2, ack = lane & 3;
    const u16* aSrc = A + (size_t)(rb + aRow) * 1024 + (ack ^ (aRow & 3)) * 8;
    f32x4 acc = {};

    auto STAGE = [&](int buf, int tt) {
        const int k0 = tt << 5;
        if (wid == 0) gload_lds16(aSrc + k0, (char*)As[buf] + lane * 16);
        gload_lds16(bSrc + k0, (char*)Bs[buf] + wid * 1024);
    };
    auto COMPUTE = [&](int buf) {
        const int row = lane & 15;
        const int sa = (lane >> 4) ^ (row & 3);
        s16x8 av = *(const s16x8*)&As[buf][row * 32 + sa * 8];
        const int col = wid * 16 + (lane & 15);
        const int sb = (lane >> 4) ^ (col & 3);
        s16x8 bv = *(const s16x8*)&Bs[buf][col * 32 + sb * 8];
        acc = MFMA(av, bv, acc);
    };

    STAGE(0, 0);
    __syncthreads();
    for (int tt = 0; tt < 32; ++tt) {
        if (tt + 1 < 32) STAGE((tt + 1) & 1, tt + 1);
        COMPUTE(tt & 1);
        __syncthreads();
    }
    // z epilogue: +bz, write bf16 z, stash f32 in LDS
    {
        const int col = wid * 16 + (lane & 15);
        const float bzc = bz[col];
        #pragma unroll
        for (int j = 0; j < 4; ++j) {
            const int row = (lane >> 4) * 4 + j;
            float v = acc[j] + bzc;
            zsh[row][col] = v;
            z[(size_t)(rb + row) * 64 + col] = f2bf(v);
        }
    }
    __syncthreads();
    // trunk L1 (K=64, f32 W2) + h1
    const int o = tid & 127;
    const int rh = (tid >> 7) * 8;
    float acc_a[8] = {}, acc_b[8] = {};
    for (int k = 0; k < 64; ++k) {
        float wa = W2[(size_t)k * LDP + o];
        float wb = W2[(size_t)k * LDP + 128 + o];
        #pragma unroll
        for (int r = 0; r < 8; ++r) {
            float zv = zsh[rh + r][k];
            acc_a[r] = fmaf(zv, wa, acc_a[r]);
            acc_b[r] = fmaf(zv, wb, acc_b[r]);
        }
    }
    #pragma unroll
    for (int r = 0; r < 8; ++r) {
        int b = rb + rh + r;
        h1[b * 128 + o] = f2bf(fast_tanh(t[b] * acc_b[r] + acc_a[r]));
    }
}

// ---------------------------------------------------------------------------
// Trunk GEMM: 512 threads / 8 waves (4Mx2N), 128x128 tile, SK=16, kz-major.
// A generated on the fly: p<8192: h[b,p>>6]*z[b,p&63]; else z[b,p-8192].
// ---------------------------------------------------------------------------
__global__ __launch_bounds__(512, 2)
void trunk128(const u16* __restrict__ h, const u16* __restrict__ z,
              const u16* __restrict__ Bt, float* __restrict__ Cp)
{
    constexpr int NT = 258, SKT = 16;
    __shared__ __align__(16) u16 As[2][128 * 32];
    __shared__ __align__(16) u16 Bs[2][128 * 32];
    const int tid = threadIdx.x, lane = tid & 63, wid = tid >> 6;
    const int wr = wid >> 1, wc = wid & 1;
    const int bm = blockIdx.y * 128, kz = blockIdx.x;
    const int t0 = (NT * kz) / SKT, t1 = (NT * (kz + 1)) / SKT;
    const int arow = tid >> 2, ck = tid & 3;
    const int b = bm + arow;
    const s16x8 zlo = *(const s16x8*)&z[b * 64 + ck * 8];
    const s16x8 zhi = *(const s16x8*)&z[b * 64 + 32 + ck * 8];
    const int slot = (ck ^ (arow & 3)) * 8;
    f32x4 acc[2][4] = {};

    auto STAGE = [&](int buf, int t) {
        const int p0 = t << 5;
        gload_lds16(Bt + (size_t)arow * 8256 + p0 + (ck ^ (arow & 3)) * 8,
                    (char*)Bs[buf] + wid * 1024);
        const s16x8 zv = (p0 & 32) ? zhi : zlo;
        u16 o8[8];
        if (p0 < 8192) {
            const float hf = bf2f(h[b * 128 + (p0 >> 6)]);
            #pragma unroll
            for (int j = 0; j < 8; ++j) o8[j] = f2bf(hf * bf2f((u16)zv[j]));
        } else {
            #pragma unroll
            for (int j = 0; j < 8; ++j) o8[j] = (u16)zv[j];
        }
        *(s16x8*)&As[buf][arow * 32 + slot] = *(s16x8*)o8;
    };
    auto COMPUTE = [&](int buf) {
        s16x8 av[2], bb[4];
        #pragma unroll
        for (int mi = 0; mi < 2; ++mi) {
            int row = wr * 32 + mi * 16 + (lane & 15);
            int s = (lane >> 4) ^ (row & 3);
            av[mi] = *(const s16x8*)&As[buf][row * 32 + s * 8];
        }
        #pragma unroll
        for (int ni = 0; ni < 4; ++ni) {
            int n = wc * 64 + ni * 16 + (lane & 15);
            int s = (lane >> 4) ^ (n & 3);
            bb[ni] = *(const s16x8*)&Bs[buf][n * 32 + s * 8];
        }
        #pragma unroll
        for (int mi = 0; mi < 2; ++mi)
        #pragma unroll
        for (int ni = 0; ni < 4; ++ni)
            acc[mi][ni] = MFMA(av[mi], bb[ni], acc[mi][ni]);
    };

    STAGE(0, t0);
    __syncthreads();
    const int nt = t1 - t0;
    for (int t = 0; t < nt; ++t) {
        if (t + 1 < nt) STAGE((t + 1) & 1, t0 + t + 1);
        COMPUTE(t & 1);
        __syncthreads();
    }

    #pragma unroll
    for (int mi = 0; mi < 2; ++mi)
    #pragma unroll
    for (int ni = 0; ni < 4; ++ni) {
        const int col = wc * 64 + ni * 16 + (lane & 15);
        #pragma unroll
        for (int jj = 0; jj < 4; ++jj) {
            const int row = bm + wr * 32 + mi * 16 + (lane >> 4) * 4 + jj;
            Cp[((size_t)kz * 2048 + row) * 128 + col] = acc[mi][ni][jj];
        }
    }
}

// ---------------------------------------------------------------------------
__global__ __launch_bounds__(256)
void reduce_tanh(const float* __restrict__ Cp, u16* __restrict__ hout) {
    const int i4 = (blockIdx.x * 256 + threadIdx.x) * 4;
    const size_t S = (size_t)2048 * 128;
    float4 s = make_float4(0.f, 0.f, 0.f, 0.f);
    #pragma unroll
    for (int k = 0; k < 16; ++k) {
        float4 v = *(const float4*)&Cp[(size_t)k * S + i4];
        s.x += v.x; s.y += v.y; s.z += v.z; s.w += v.w;
    }
    uint2 o;
    o.x = (u32)f2bf(fast_tanh(s.x)) | ((u32)f2bf(fast_tanh(s.y)) << 16);
    o.y = (u32)f2bf(fast_tanh(s.z)) | ((u32)f2bf(fast_tanh(s.w)) << 16);
    *(uint2*)&hout[i4] = o;
}

__global__ __launch_bounds__(256)
void reduce_out(const float* __restrict__ Cp, const u16* __restrict__ z,
                const float* __restrict__ W2, const float* __restrict__ t,
                const float* __restrict__ u, float* __restrict__ out)
{
    __shared__ float sh[4][128];
    const int wv = threadIdx.x >> 6, l = threadIdx.x & 63;
    const int b = blockIdx.x * 4 + wv;
    const size_t S = (size_t)2048 * 128;
    #pragma unroll
    for (int e = l; e < 128; e += 64) {
        float s = 0.f;
        #pragma unroll
        for (int k = 0; k < 16; ++k) s += Cp[k * S + (size_t)b * 128 + e];
        sh[wv][e] = fast_tanh(s);
    }
    __syncthreads();
    const float* wrow = &W2[(size_t)l * LDP + 33280];
    float acc = wrow[0];
    #pragma unroll 8
    for (int i = 0; i < 128; ++i) acc = fmaf(sh[wv][i], wrow[1 + i], acc);
    float p = bf2f(z[b * 64 + l]) * acc;
    #pragma unroll
    for (int off = 32; off > 0; off >>= 1) p += __shfl_down(p, off);
    if (l == 0) out[b] = u[b * 128] + t[b] * p;
}

// ---------------------------------------------------------------------------
extern "C" void kernel_launch(void* const* d_in, const int* in_sizes, int n_in,
                              void* d_out, int out_size, void* d_ws, size_t ws_size,
                              hipStream_t stream)
{
    const float* t   = (const float*)d_in[0];
    const float* u   = (const float*)d_in[1];
    const float* bw0 = (const float*)d_in[2];
    const float* bb0 = (const float*)d_in[3];
    const float* bw1 = (const float*)d_in[4];
    const float* bb1 = (const float*)d_in[5];
    const float* bw2 = (const float*)d_in[6];
    const float* bb2 = (const float*)d_in[7];
    const float* bw3 = (const float*)d_in[8];
    const float* bb3 = (const float*)d_in[9];
    const float* bw4 = (const float*)d_in[10];
    const float* bb4 = (const float*)d_in[11];
    const float* W1  = (const float*)d_in[12];
    const float* W2  = (const float*)d_in[13];
    float* out = (float*)d_out;

    char* base = (char*)d_ws;
    u16*   bw1t = (u16*)(base);                  // 2 MB
    u16*   bw2t = (u16*)(base + 2097152);        // 2 MB
    u16*   bw3t = (u16*)(base + 4194304);        // 2 MB
    u16*   actA = (u16*)(base + 6291456);        // 4 MB
    u16*   actB = (u16*)(base + 10485760);       // 4 MB
    u16*   BWt  = (u16*)(base + 15499264);       // 128 KB
    float* bz   = (float*)(base + 15630336);     // 256 B
    u16*   z    = (u16*)(base + 16777216);       // 256 KB
    u16*   h1   = (u16*)(base + 17039360);       // 512 KB
    u16*   h2   = (u16*)(base + 17563648);       // 512 KB
    u16*   Bt   = (u16*)(base + 18087936);       // 4,227,072 (2 layers)
    float* Cp   = (float*)(base);                // overlay: 16.78 MB

    dim3 blk(256);
    // ---- L0 (inline f32 staging) + T(bw1) + gather Bt
    gemm_l0<<<1028, blk, 0, stream>>>(u, bw0, bb0, actA, bw1, bw1t, W2, Bt);
    // ---- branch L1/L2 with horizontal prep
    gemm_fused<<<512, blk, 0, stream>>>(                       // L1 + T(bw2)
        actA, 1024, bw1t, 1024, bb1, actB, 1024, 1024, 1,
        bw2, bw2t, bw4, bb4, W1, BWt, bz);
    gemm_fused<<<1025, blk, 0, stream>>>(                      // L2 + T(bw3) + BW + bz
        actB, 1024, bw2t, 1024, bb2, actA, 1024, 1024, 2,
        bw3, bw3t, bw4, bb4, W1, BWt, bz);
    // ---- L3 pure GEMM (64x64, 512 blocks)
    gemm_plain<<<dim3(16, 32), blk, 0, stream>>>(actA, bw3t, bb3, actB);
    // ---- fused z-GEMM + trunk L1 + h1 (one dispatch, full K)
    z_h1<<<128, blk, 0, stream>>>(actB, BWt, bz, W2, t, z, h1);
    // ---- trunk layers 2,3
    trunk128<<<dim3(16, 16), dim3(512), 0, stream>>>(h1, z, Bt, Cp);
    reduce_tanh<<<256, blk, 0, stream>>>(Cp, h2);
    trunk128<<<dim3(16, 16), dim3(512), 0, stream>>>(h2, z, Bt + (size_t)128 * 8256, Cp);
    // ---- layer-3 reduce + trunk L4 + combine
    reduce_out<<<512, blk, 0, stream>>>(Cp, z, W2, t, u, out);
}